// Round 4
// baseline (1148.486 us; speedup 1.0000x reference)
//
#include <hip/hip_runtime.h>
#include <math.h>

#define BB 4
#define TT 10
#define NN 4096
#define HH 32
#define JP 144                    // padded j (132 real: 4 b * 33 kk)
#define NH (NN*HH)                // 131072
#define NPAIR (NN*NN/2)           // 8388608 (fp16 pairs / u32 words)
#define QPL (BB*NN*64)            // 1048576: one [b][m][64] plane of Q/G

typedef __attribute__((ext_vector_type(8))) short short8;
typedef __attribute__((ext_vector_type(8))) _Float16 half8;
typedef __attribute__((ext_vector_type(4))) float floatx4;
typedef __attribute__((ext_vector_type(4))) unsigned int uintx4;
typedef __attribute__((ext_vector_type(2))) unsigned int uintx2;

__device__ inline unsigned short f2h(float f) {
    _Float16 h = (_Float16)f;                  // v_cvt_f16_f32, RNE
    unsigned short u; __builtin_memcpy(&u, &h, 2);
    return u;
}
__device__ inline unsigned pk2(float a, float b) {
    return (unsigned)f2h(a) | ((unsigned)f2h(b) << 16);
}

// ---------- merged prep: pack A streams  +  build Ct pass1 (+pad zero) ----------
__global__ void k_prep(const float* __restrict__ dtw, const float* __restrict__ tdl,
                       const float* __restrict__ spl, const float* __restrict__ lap,
                       const float* __restrict__ inp, const float* __restrict__ st,
                       unsigned* __restrict__ Aoff, unsigned* __restrict__ Aon,
                       unsigned* __restrict__ A9, unsigned short* __restrict__ thr2,
                       unsigned short* __restrict__ Ct) {
    int bx = blockIdx.x;
    int tid = threadIdx.x;
    if (bx < NPAIR / 256) {
        // ---- pack: A_off=spl+I, A_on=off+dtw, A9=off+masked dtw+lap, thr u8 ----
        int e = bx * 256 + tid;                  // pair index
        size_t gi = (size_t)e * 2;
        int row = (int)(gi >> 12);
        int c0 = (int)(gi & 4095);
        float2 d = ((const float2*)dtw)[e];
        float2 td = ((const float2*)tdl)[e];
        float2 s = ((const float2*)spl)[e];
        float2 l = ((const float2*)lap)[e];
        float td0 = ceilf(fabsf(td.x)), td1 = ceilf(fabsf(td.y));
        int th0 = 10 - (int)td0; if (th0 < 0) th0 = 0;
        int th1 = 10 - (int)td1; if (th1 < 0) th1 = 0;
        float off0 = s.x + ((row == c0) ? 1.f : 0.f);
        float off1 = s.y + ((row == c0 + 1) ? 1.f : 0.f);
        float on0 = off0 + d.x, on1 = off1 + d.y;
        float a90 = off0 + l.x + ((td0 > 0.f && d.x != 0.f) ? d.x : 0.f);
        float a91 = off1 + l.y + ((td1 > 0.f && d.y != 0.f) ? d.y : 0.f);
        Aoff[e] = pk2(off0, off1);
        Aon[e]  = pk2(on0, on1);
        A9[e]   = pk2(a90, a91);
        thr2[e] = (unsigned short)(th0 | (th1 << 8));
    } else {
        // ---- build Ct[t][j][n] fp16, scale folded (h raw) + zero pad rows ----
        int r = bx - NPAIR / 256;                // 0..1279
        int nb = r & 31, b = (r >> 5) & 3, t = r >> 7;
        float sc = (t == TT - 1) ? (1.f / 3.f) : 0.5f;
        int kk = tid & 31;
        int ng = tid >> 5;
        const float* stb = st + (size_t)(t * BB + b) * NH;
        unsigned short* crow = Ct + (size_t)(t * JP + b * 33 + 1 + kk) * NN;
        int n0 = nb * 128 + ng * 16;
#pragma unroll
        for (int i = 0; i < 16; i++) {
            int n = n0 + i;
            crow[n] = f2h(stb[n * 32 + kk] * sc);
        }
        if (tid < 128) {
            int n = nb * 128 + tid;
            Ct[(size_t)(t * JP + b * 33) * NN + n] = f2h(inp[((size_t)b * TT + t) * NN + n] * sc);
        }
        if (b == 0) {                            // pad rows j in [132,144)
            for (int l = tid; l < 12 * 128; l += 256) {
                int j = 132 + (l >> 7);
                int n = nb * 128 + (l & 127);
                Ct[(size_t)(t * JP + j) * NN + n] = 0;
            }
        }
    }
}

// ---------- build Ct pass2: h replaced by r*h, r = sigmoid(gcn1 flat) ----------
__global__ void k_build_ct2(const float* __restrict__ inp, const float* __restrict__ st,
                            const float* __restrict__ G, unsigned short* __restrict__ Ct) {
    int nb = blockIdx.x, b = blockIdx.y, t = blockIdx.z;
    int tid = threadIdx.x;
    float sc = (t == TT - 1) ? (1.f / 3.f) : 0.5f;
    int kk = tid & 31;
    int ng = tid >> 5;
    const float* stb = st + (size_t)(t * BB + b) * NH;
    const float* Gb = G + (size_t)(t * BB + b) * NN * 64;   // flat index == jj
    unsigned short* crow = Ct + (size_t)(t * JP + b * 33 + 1 + kk) * NN;
    int n0 = nb * 128 + ng * 16;
#pragma unroll
    for (int i = 0; i < 16; i++) {
        int n = n0 + i;
        int jj = n * 32 + kk;
        float g = Gb[jj];
        float r = 1.0f / (1.0f + expf(-g));
        crow[n] = f2h(r * stb[jj] * sc);
    }
    if (tid < 128) {
        int n = nb * 128 + tid;
        Ct[(size_t)(t * JP + b * 33) * NN + n] = f2h(inp[((size_t)b * TT + t) * NN + n] * sc);
    }
}

// ---------- v2 GEMM core (best measured: 143 us/dispatch) ----------
// 128-row tiles, LDS double-buffer, ONE barrier per K-step, register prefetch keeps
// global loads in flight across the barrier (lgkmcnt-only wait; no vmcnt drain).
__device__ __forceinline__ void gemm_core(
        int t, int ks, int m0, int tid,
        const unsigned* __restrict__ Aoff, const unsigned* __restrict__ Aon,
        const unsigned* __restrict__ A9, const unsigned short* __restrict__ thr2,
        const unsigned* __restrict__ Ct, short* __restrict__ As, short* __restrict__ Cs,
        floatx4 (&acc)[2][9]) {
    int w = tid >> 6, lane = tid & 63;
    int lm = lane & 15, q = lane >> 4;

#pragma unroll
    for (int i = 0; i < 2; i++)
#pragma unroll
        for (int j = 0; j < 9; j++) acc[i][j] = (floatx4){0.f, 0.f, 0.f, 0.f};

    const bool last = (t == TT - 1);
    const int arow0 = tid >> 2;              // 0..63
    const int arow1 = arow0 + 64;            // 64..127
    const int ac = (tid & 3) * 4;            // u32 col within row-chunk of 16
    const size_t kbase = (size_t)ks * 1024;  // u32 col base of this k-split
    const size_t ga0 = (size_t)(m0 + arow0) * 2048 + kbase + ac;
    const size_t ga1 = (size_t)(m0 + arow1) * 2048 + kbase + ac;
    const int cj0 = arow0;
    const int cj1 = arow0 + 64;
    const int cj2 = arow0 + 128;             // wave 0 only
    const unsigned* CtT = Ct + (size_t)t * JP * 2048 + kbase;

    uintx4 pO0, pO1, pA0, pA1, rC0, rC1, rC2;
    uintx2 pT0, pT1;

    auto LOADS = [&](int ku) {
        if (last) {
            pO0 = *(const uintx4*)(A9 + ga0 + ku);
            pO1 = *(const uintx4*)(A9 + ga1 + ku);
        } else {
            pO0 = *(const uintx4*)(Aoff + ga0 + ku);
            pA0 = *(const uintx4*)(Aon  + ga0 + ku);
            pT0 = *(const uintx2*)(thr2 + ga0 + ku);
            pO1 = *(const uintx4*)(Aoff + ga1 + ku);
            pA1 = *(const uintx4*)(Aon  + ga1 + ku);
            pT1 = *(const uintx2*)(thr2 + ga1 + ku);
        }
        rC0 = *(const uintx4*)(CtT + (size_t)cj0 * 2048 + ku + ac);
        rC1 = *(const uintx4*)(CtT + (size_t)cj1 * 2048 + ku + ac);
        if (tid < 64) rC2 = *(const uintx4*)(CtT + (size_t)cj2 * 2048 + ku + ac);
    };

    auto SEL = [&](uintx4& dst, const uintx4& po, const uintx4& pa, const uintx2& pt) {
#pragma unroll
        for (int u = 0; u < 4; u++) {
            unsigned th = ((u < 2) ? pt[0] : pt[1]) >> ((u & 1) * 16);
            unsigned lo = ((int)(th & 255u) <= t) ? pa[u] : po[u];
            unsigned hi = ((int)((th >> 8) & 255u) <= t) ? pa[u] : po[u];
            dst[u] = (lo & 0xFFFFu) | (hi & 0xFFFF0000u);
        }
    };

    LOADS(0);
    int p = 0;
    for (int kb = 0; kb < 64; kb++) {
        short* Asb = As + p * 5120;
        short* Csb = Cs + p * 5760;
        unsigned* Asu = (unsigned*)Asb;
        unsigned* Csu = (unsigned*)Csb;
        uintx4 r0, r1;
        if (last) { r0 = pO0; r1 = pO1; }
        else { SEL(r0, pO0, pA0, pT0); SEL(r1, pO1, pA1, pT1); }
        *(uintx4*)(Asu + arow0 * 20 + ac) = r0;
        *(uintx4*)(Asu + arow1 * 20 + ac) = r1;
        *(uintx4*)(Csu + cj0 * 20 + ac) = rC0;
        *(uintx4*)(Csu + cj1 * 20 + ac) = rC1;
        if (tid < 64) *(uintx4*)(Csu + cj2 * 20 + ac) = rC2;
        if (kb < 63) LOADS((kb + 1) * 16);
        asm volatile("s_waitcnt lgkmcnt(0)" ::: "memory");
        __builtin_amdgcn_s_barrier();
        asm volatile("" ::: "memory");
        short8 a0v = *(const short8*)(Asb + (w * 32 + lm) * 40 + q * 8);
        short8 a1v = *(const short8*)(Asb + (w * 32 + 16 + lm) * 40 + q * 8);
        half8 ah0 = __builtin_bit_cast(half8, a0v);
        half8 ah1 = __builtin_bit_cast(half8, a1v);
#pragma unroll
        for (int jt = 0; jt < 9; jt++) {
            short8 bv = *(const short8*)(Csb + (jt * 16 + lm) * 40 + q * 8);
            half8 bh = __builtin_bit_cast(half8, bv);
            acc[0][jt] = __builtin_amdgcn_mfma_f32_16x16x32_f16(ah0, bh, acc[0][jt], 0, 0, 0);
            acc[1][jt] = __builtin_amdgcn_mfma_f32_16x16x32_f16(ah1, bh, acc[1][jt], 0, 0, 0);
        }
        p ^= 1;
    }
}

// ---------- MFMA GEMM + fused linear epilogue ----------
// PASS==1: dst = Qp, epilogue projects the 128x144 tile through W1 (33x64) and writes
//          Qp[ks][t][b][row][64]  (Q_t = O_t @ W1; prefix+bias applied later in k_mid).
// PASS==2: dst = F,  epilogue projects through W2 (33x32) and atomicAdds into
//          F[b][row][32]  (sum over t and ks -- projection is linear, so
//          project-then-sum == sum-then-project).
// Epilogue method: each wave scatters its 16-row acc tile (col=lane&15,
// row=(lane>>4)*4+r) into a private LDS region (row-major, stride 148 f32), then
// lane -> (rr=lane>>2, b=lane&3) reads its 33-float P row into regs and FMAs against
// wave-uniform W rows (scalar loads). No O buffer, no k_gcn1/k_prefix/k_reduce kernels.
template <int PASS>
__global__ __launch_bounds__(256) void k_mfma(const unsigned* __restrict__ Aoff,
                                              const unsigned* __restrict__ Aon,
                                              const unsigned* __restrict__ A9,
                                              const unsigned short* __restrict__ thr2,
                                              const unsigned* __restrict__ Ct,
                                              const float* __restrict__ Wm,
                                              float* __restrict__ dst) {
    int t = blockIdx.z;
    int ks = blockIdx.y;
    int m0 = blockIdx.x * 128;
    int tid = threadIdx.x;
    int w = tid >> 6, lane = tid & 63;
    int lm = lane & 15, q = lane >> 4;

    __shared__ __align__(16) short smem[21760];   // 43520 B: As 2x5120 | Cs 2x5760 shorts
    short* As = smem;
    short* Cs = smem + 10240;

    floatx4 acc[2][9];
    gemm_core(t, ks, m0, tid, Aoff, Aon, A9, thr2, Ct, As, Cs, acc);

    __syncthreads();                              // all GEMM LDS reads done; reuse smem
    float* Pw = (float*)smem + w * (16 * 148);    // per-wave 16x148 f32 region (37888 B)
    const int rr = lane >> 2, bq = lane & 3;

#pragma unroll
    for (int mt = 0; mt < 2; mt++) {
        __syncthreads();
        // scatter acc tile: rows q*4+r (0..15), cols jt*16+lm (0..143)
#pragma unroll
        for (int jt = 0; jt < 9; jt++)
#pragma unroll
            for (int r = 0; r < 4; r++)
                Pw[(q * 4 + r) * 148 + jt * 16 + lm] = acc[mt][jt][r];
        // gather this lane's P row (DS ops are in-order within a wave)
        float P[33];
#pragma unroll
        for (int kk = 0; kk < 33; kk++) P[kk] = Pw[rr * 148 + bq * 33 + kk];
        int grow = m0 + w * 32 + mt * 16 + rr;
        if (PASS == 1) {
            float* drow = dst + ((size_t)(ks * TT + t) * 4 + bq) * (size_t)(NN * 64)
                              + (size_t)grow * 64;
#pragma unroll
            for (int qc = 0; qc < 4; qc++) {
                float o[16];
#pragma unroll
                for (int qi = 0; qi < 16; qi++) o[qi] = 0.f;
                for (int kk = 0; kk < 33; kk++) {
                    float pv = P[kk];
                    const float* wrow = Wm + kk * 64 + qc * 16;   // wave-uniform -> s_load
#pragma unroll
                    for (int qi = 0; qi < 16; qi++) o[qi] = fmaf(pv, wrow[qi], o[qi]);
                }
#pragma unroll
                for (int qi = 0; qi < 16; qi++) drow[qc * 16 + qi] = o[qi];
            }
        } else {
            float* frow = dst + (size_t)bq * (size_t)(NN * 32) + (size_t)grow * 32;
#pragma unroll
            for (int qc = 0; qc < 2; qc++) {
                float o[16];
#pragma unroll
                for (int qi = 0; qi < 16; qi++) o[qi] = 0.f;
                for (int kk = 0; kk < 33; kk++) {
                    float pv = P[kk];
                    const float* wrow = Wm + kk * 32 + qc * 16;
#pragma unroll
                    for (int qi = 0; qi < 16; qi++) o[qi] = fmaf(pv, wrow[qi], o[qi]);
                }
#pragma unroll
                for (int qi = 0; qi < 16; qi++) atomicAdd(&frow[qc * 16 + qi], o[qi]);
            }
        }
    }
}

// ---------- mid: G[t] = (t+1)*b1 + prefix_t(Qp[0]+Qp[1]);  zero F ----------
__global__ void k_mid(const float* __restrict__ Qp, const float* __restrict__ b1,
                      float* __restrict__ G, float* __restrict__ F) {
    int e = blockIdx.x * 256 + threadIdx.x;       // over QPL = [b][m][64]
    float bb = b1[e & 63];
    float run = 0.f;
#pragma unroll
    for (int t = 0; t < TT; t++) {
        run += Qp[(size_t)t * QPL + e] + Qp[(size_t)(TT + t) * QPL + e];
        G[(size_t)t * QPL + e] = (float)(t + 1) * bb + run;
    }
    if (e < BB * NN * 32) F[e] = 0.f;             // zero-init pass-2 accumulator
}

// ---------- epilogue: c = tanh(F + 10*b2), u-gate ----------
__global__ __launch_bounds__(256) void k_final(const float* __restrict__ F,
                                               const float* __restrict__ G,
                                               const float* __restrict__ st,
                                               const float* __restrict__ b2,
                                               float* __restrict__ out) {
    int e = blockIdx.x * 256 + threadIdx.x;       // over B*N*H
    int b = e >> 17;
    int jj = e & (NH - 1);
    int qq = jj & 31;
    float a = 10.0f * b2[qq] + F[e];
    float c = tanhf(a);
    float gu = G[(size_t)((9 * BB + b) * NN + 2048 + (jj >> 6)) * 64 + (jj & 63)];
    float u = 1.0f / (1.0f + expf(-gu));
    float h = st[(size_t)(9 * BB + b) * NH + jj];
    out[e] = u * h + (1.0f - u) * c;
}

extern "C" void kernel_launch(void* const* d_in, const int* in_sizes, int n_in,
                              void* d_out, int out_size, void* d_ws, size_t ws_size,
                              hipStream_t stream) {
    const float* inp = (const float*)d_in[0];
    const float* st  = (const float*)d_in[1];
    const float* dtw = (const float*)d_in[2];
    const float* spl = (const float*)d_in[3];
    const float* lap = (const float*)d_in[4];
    const float* tdl = (const float*)d_in[5];
    const float* W1  = (const float*)d_in[6];
    const float* b1  = (const float*)d_in[7];
    const float* W2  = (const float*)d_in[8];
    const float* b2  = (const float*)d_in[9];
    float* out = (float*)d_out;

    char* W = (char*)d_ws;
    unsigned*       Aoff = (unsigned*)W;                     W += (size_t)NPAIR * 4;
    unsigned*       Aon  = (unsigned*)W;                     W += (size_t)NPAIR * 4;
    unsigned*       A9   = (unsigned*)W;                     W += (size_t)NPAIR * 4;
    unsigned short* thr2 = (unsigned short*)W;               W += (size_t)NPAIR * 2;
    unsigned short* Ct   = (unsigned short*)W;               W += (size_t)TT * JP * NN * 2;
    float*          Qp   = (float*)W;                        W += (size_t)2 * TT * QPL * 4;
    float*          G    = (float*)W;                        W += (size_t)TT * QPL * 4;
    float*          F    = (float*)W;                        W += (size_t)BB * NN * 32 * 4;

    k_prep<<<NPAIR / 256 + 1280, 256, 0, stream>>>(dtw, tdl, spl, lap, inp, st,
                                                   Aoff, Aon, A9, thr2, Ct);

    dim3 gmm(NN / 128, 2, TT);
    k_mfma<1><<<gmm, 256, 0, stream>>>(Aoff, Aon, A9, thr2, (const unsigned*)Ct, W1, Qp);

    k_mid<<<QPL / 256, 256, 0, stream>>>(Qp, b1, G, F);

    dim3 gbld(NN / 128, BB, TT);
    k_build_ct2<<<gbld, 256, 0, stream>>>(inp, st, G, Ct);

    k_mfma<2><<<gmm, 256, 0, stream>>>(Aoff, Aon, A9, thr2, (const unsigned*)Ct, W2, F);

    k_final<<<(BB * NN * HH) / 256, 256, 0, stream>>>(F, G, st, b2, out);
}